// Round 1
// baseline (1766.743 us; speedup 1.0000x reference)
//
#include <hip/hip_runtime.h>

#define D 64
#define SCAN_BS 1024

// ---------------- CSR build ----------------

__global__ void count_deg_kernel(const int* __restrict__ dst, int* __restrict__ counts, int nnz) {
    int e = blockIdx.x * blockDim.x + threadIdx.x;
    if (e < nnz) atomicAdd(&counts[dst[e]], 1);
}

__global__ void scan_blocks_kernel(const int* __restrict__ counts, int* __restrict__ offs,
                                   int* __restrict__ partials, int n) {
    __shared__ int sh[SCAN_BS];
    int tid = threadIdx.x;
    int i = blockIdx.x * SCAN_BS + tid;
    int v = (i < n) ? counts[i] : 0;
    sh[tid] = v;
    __syncthreads();
    for (int ofs = 1; ofs < SCAN_BS; ofs <<= 1) {
        int t = (tid >= ofs) ? sh[tid - ofs] : 0;
        __syncthreads();
        sh[tid] += t;
        __syncthreads();
    }
    if (i < n) offs[i] = sh[tid] - v;  // exclusive within block
    if (tid == SCAN_BS - 1) partials[blockIdx.x] = sh[tid];
}

__global__ void scan_partials_kernel(int* partials, int nb) {
    __shared__ int sh[SCAN_BS];
    int tid = threadIdx.x;
    int v = (tid < nb) ? partials[tid] : 0;
    sh[tid] = v;
    __syncthreads();
    for (int ofs = 1; ofs < SCAN_BS; ofs <<= 1) {
        int t = (tid >= ofs) ? sh[tid - ofs] : 0;
        __syncthreads();
        sh[tid] += t;
        __syncthreads();
    }
    if (tid < nb) partials[tid] = sh[tid] - v;  // exclusive
}

__global__ void add_base_kernel(int* __restrict__ offs, const int* __restrict__ partials,
                                int n, int nnz) {
    int i = blockIdx.x * SCAN_BS + threadIdx.x;
    if (i < n) offs[i] += partials[blockIdx.x];
    if (blockIdx.x == 0 && threadIdx.x == 0) offs[n] = nnz;
}

__global__ void fill_csr_kernel(const int* __restrict__ src, const int* __restrict__ dst,
                                const float* __restrict__ val, int* __restrict__ cursor,
                                float* __restrict__ csr_val, int* __restrict__ csr_src, int nnz) {
    int e = blockIdx.x * blockDim.x + threadIdx.x;
    if (e >= nnz) return;
    int d = dst[e];
    int p = atomicAdd(&cursor[d], 1);
    csr_val[p] = val[e];
    csr_src[p] = src[e];
}

// ---------------- SpMM: one wave per dst node, lane = feature ----------------

template <bool FIRST>
__global__ void spmm_kernel(const int* __restrict__ offs, const float* __restrict__ csr_val,
                            const int* __restrict__ csr_src, const float* __restrict__ x_in,
                            const float* __restrict__ user_emb, const float* __restrict__ item_emb,
                            float* __restrict__ x_out, float* __restrict__ acc,
                            int n_nodes, int n_users) {
    int wave = (int)((blockIdx.x * blockDim.x + threadIdx.x) >> 6);
    int lane = threadIdx.x & 63;
    if (wave >= n_nodes) return;
    int e0 = offs[wave], e1 = offs[wave + 1];
    float sum = 0.f;
    for (int base = e0; base < e1; base += 64) {
        int e = base + lane;
        float v = 0.f;
        int s = 0;
        if (e < e1) { v = csr_val[e]; s = csr_src[e]; }  // coalesced chunk load
        int cnt = min(64, e1 - base);
        for (int j = 0; j < cnt; ++j) {
            float vj = __shfl(v, j);
            int sj = __shfl(s, j);
            const float* row;
            if (FIRST)
                row = (sj < n_users) ? (user_emb + (size_t)sj * D)
                                     : (item_emb + (size_t)(sj - n_users) * D);
            else
                row = x_in + (size_t)sj * D;
            sum = fmaf(vj, row[lane], sum);  // 256B coalesced gather per edge
        }
    }
    int oi = wave * D + lane;
    x_out[oi] = sum;
    acc[oi] += sum;
}

// ---------------- Rating GEMM: (batch x 64) * (64 x n_items), fp32 ----------------

#define BM 128
#define BN 128
#define TM 8
#define TN 8
#define KB 32
#define PAD 4

__global__ __launch_bounds__(256) void rating_gemm_kernel(
        const float* __restrict__ acc, const int* __restrict__ users,
        float* __restrict__ out, int n_users, int n_items, int batch) {
    __shared__ __align__(16) float As[KB][BM + PAD];
    __shared__ __align__(16) float Bs[KB][BN + PAD];
    int m0 = blockIdx.y * BM;
    int n0 = blockIdx.x * BN;
    int tid = threadIdx.x;
    int tx = tid & 15, ty = tid >> 4;
    float c[TM][TN] = {};

    for (int k0 = 0; k0 < D; k0 += KB) {
        // stage A: BM user rows x KB k (float4 along k, transposed into [k][m])
        for (int f = tid; f < BM * (KB / 4); f += 256) {
            int m = f >> 3;
            int k4 = (f & 7) * 4;
            float4 a = make_float4(0.f, 0.f, 0.f, 0.f);
            int gm = m0 + m;
            if (gm < batch) {
                int uid = users[gm];
                a = *(const float4*)(acc + (size_t)uid * D + k0 + k4);
            }
            As[k4 + 0][m] = a.x; As[k4 + 1][m] = a.y;
            As[k4 + 2][m] = a.z; As[k4 + 3][m] = a.w;
        }
        // stage B: BN item rows x KB k
        for (int f = tid; f < BN * (KB / 4); f += 256) {
            int n = f >> 3;
            int k4 = (f & 7) * 4;
            float4 b = make_float4(0.f, 0.f, 0.f, 0.f);
            int gi = n0 + n;
            if (gi < n_items) {
                b = *(const float4*)(acc + (size_t)(n_users + gi) * D + k0 + k4);
            }
            Bs[k4 + 0][n] = b.x; Bs[k4 + 1][n] = b.y;
            Bs[k4 + 2][n] = b.z; Bs[k4 + 3][n] = b.w;
        }
        __syncthreads();
        #pragma unroll
        for (int k = 0; k < KB; ++k) {
            float a[TM], b[TN];
            float4 t;
            t = *(const float4*)&As[k][ty * TM];     a[0] = t.x; a[1] = t.y; a[2] = t.z; a[3] = t.w;
            t = *(const float4*)&As[k][ty * TM + 4]; a[4] = t.x; a[5] = t.y; a[6] = t.z; a[7] = t.w;
            t = *(const float4*)&Bs[k][tx * TN];     b[0] = t.x; b[1] = t.y; b[2] = t.z; b[3] = t.w;
            t = *(const float4*)&Bs[k][tx * TN + 4]; b[4] = t.x; b[5] = t.y; b[6] = t.z; b[7] = t.w;
            #pragma unroll
            for (int i = 0; i < TM; ++i)
                #pragma unroll
                for (int j = 0; j < TN; ++j)
                    c[i][j] = fmaf(a[i], b[j], c[i][j]);
        }
        __syncthreads();
    }

    const float S = 1.0f / 16.0f;  // (acc/4)·(acc/4)
    for (int i = 0; i < TM; ++i) {
        int m = m0 + ty * TM + i;
        if (m >= batch) break;
        float* row = out + (size_t)m * n_items;
        for (int j = 0; j < TN; j += 4) {
            int n = n0 + tx * TN + j;
            if (n + 4 <= n_items) {
                float4 v;
                v.x = c[i][j + 0] * S; v.y = c[i][j + 1] * S;
                v.z = c[i][j + 2] * S; v.w = c[i][j + 3] * S;
                *(float4*)(row + n) = v;
            } else {
                for (int u = 0; u < 4; ++u)
                    if (n + u < n_items) row[n + u] = c[i][j + u] * S;
            }
        }
    }
}

// ---------------- launcher ----------------

extern "C" void kernel_launch(void* const* d_in, const int* in_sizes, int n_in,
                              void* d_out, int out_size, void* d_ws, size_t ws_size,
                              hipStream_t stream) {
    const float* user_emb = (const float*)d_in[0];
    const float* item_emb = (const float*)d_in[1];
    const float* edge_val = (const float*)d_in[2];
    const int*   edge_src = (const int*)d_in[3];
    const int*   edge_dst = (const int*)d_in[4];
    const int*   users    = (const int*)d_in[5];

    const int n_users = in_sizes[0] / D;   // 100000
    const int n_items = in_sizes[1] / D;   // 50000
    const int nnz     = in_sizes[2];       // 4000000
    const int batch   = in_sizes[5];       // 2048
    const int n_nodes = n_users + n_items; // 150000

    // workspace carve-out (~149 MB)
    char* w = (char*)d_ws;
    size_t off = 0;
    auto alloc = [&](size_t bytes) -> void* {
        void* p = w + off;
        off += (bytes + 255) & ~(size_t)255;
        return p;
    };
    float* acc      = (float*)alloc((size_t)n_nodes * D * 4);
    float* xA       = (float*)alloc((size_t)n_nodes * D * 4);
    float* xB       = (float*)alloc((size_t)n_nodes * D * 4);
    int*   counts   = (int*)alloc((size_t)n_nodes * 4);
    int*   offs     = (int*)alloc((size_t)(n_nodes + 1) * 4);
    int*   partials = (int*)alloc((size_t)SCAN_BS * 4);
    int*   cursor   = (int*)alloc((size_t)n_nodes * 4);
    float* csr_val  = (float*)alloc((size_t)nnz * 4);
    int*   csr_src  = (int*)alloc((size_t)nnz * 4);
    (void)ws_size; (void)n_in; (void)out_size;

    // acc = concat(user_emb, item_emb)
    hipMemcpyAsync(acc, user_emb, (size_t)n_users * D * 4, hipMemcpyDeviceToDevice, stream);
    hipMemcpyAsync(acc + (size_t)n_users * D, item_emb, (size_t)n_items * D * 4,
                   hipMemcpyDeviceToDevice, stream);

    // CSR by dst
    hipMemsetAsync(counts, 0, (size_t)n_nodes * 4, stream);
    count_deg_kernel<<<(nnz + 255) / 256, 256, 0, stream>>>(edge_dst, counts, nnz);
    int nb = (n_nodes + SCAN_BS - 1) / SCAN_BS;
    scan_blocks_kernel<<<nb, SCAN_BS, 0, stream>>>(counts, offs, partials, n_nodes);
    scan_partials_kernel<<<1, SCAN_BS, 0, stream>>>(partials, nb);
    add_base_kernel<<<nb, SCAN_BS, 0, stream>>>(offs, partials, n_nodes, nnz);
    hipMemcpyAsync(cursor, offs, (size_t)n_nodes * 4, hipMemcpyDeviceToDevice, stream);
    fill_csr_kernel<<<(nnz + 255) / 256, 256, 0, stream>>>(edge_src, edge_dst, edge_val,
                                                           cursor, csr_val, csr_src, nnz);

    // 3 SpMM layers, acc += each
    int spmm_blocks = (n_nodes + 3) / 4;  // 4 waves per 256-thread block
    spmm_kernel<true><<<spmm_blocks, 256, 0, stream>>>(offs, csr_val, csr_src, nullptr,
                                                       user_emb, item_emb, xA, acc,
                                                       n_nodes, n_users);
    spmm_kernel<false><<<spmm_blocks, 256, 0, stream>>>(offs, csr_val, csr_src, xA,
                                                        nullptr, nullptr, xB, acc,
                                                        n_nodes, n_users);
    spmm_kernel<false><<<spmm_blocks, 256, 0, stream>>>(offs, csr_val, csr_src, xB,
                                                        nullptr, nullptr, xA, acc,
                                                        n_nodes, n_users);

    // rating = users_emb @ items^T / 16
    dim3 ggrid((n_items + BN - 1) / BN, (batch + BM - 1) / BM);
    rating_gemm_kernel<<<ggrid, 256, 0, stream>>>(acc, users, (float*)d_out,
                                                  n_users, n_items, batch);
}